// Round 16
// baseline (1275.004 us; speedup 1.0000x reference)
//
#include <hip/hip_runtime.h>
#include <math.h>

// 3-layer LSTM (H=64, T=512, B=2048, Din=16), R16: deferred hseq store.
// R15 post-mortem: recurrent loop is latency-bound (~2430 cyc/iter wall vs
// ~1000 issue); removing work (R15 vs R11) made layers SLOWER. The removable
// stall: cell phase ends with hseq global store -> s_waitcnt vmcnt(0) ->
// barrier, putting the HBM store-ack (~100-200 cyc) naked on the critical
// path every iteration. R16 defers the store one iteration: cell keeps the
// packed value in a register; next iter's w1 issues the store FIRST, so the
// drain overlaps the MFMA/LDS phase. Addresses/values unchanged (determinism
// + absmax preserved); slot-t store now at iter t+1 vs its read at iter t-4
// (5-iter separation). Final store flushed after the loop.
// Everything else identical to R15 (best: 1265us).

#define T_STEPS 512
#define BATCH   2048
#define HID     64
#define NG      256
#define CB      8
#define NTHR    1024
#define SEQS    (BATCH * HID)     // hseq u32 elements per timestep

typedef __attribute__((ext_vector_type(8))) _Float16 f16x8;
typedef __attribute__((ext_vector_type(4))) float f32x4;

__device__ __forceinline__ float sigm(float z) { return 1.0f / (1.0f + __expf(-z)); }
__device__ __forceinline__ float tanh_f(float z) {
    z = fminf(15.0f, fmaxf(-15.0f, z));
    const float e = __expf(2.0f * z);
    return (e - 1.0f) / (e + 1.0f);
}
// truncate f32 -> bf16 (lo term captures the remainder)
__device__ __forceinline__ short tb(float v) { return (short)(__float_as_uint(v) >> 16); }
__device__ __forceinline__ float fb(unsigned h) {
    return __uint_as_float((h & 0xffffu) << 16);
}
// 8-row 128B/row fp16 plane, XOR-swizzled 16B units; rows alias &7
__device__ __forceinline__ int ha(int row, int u8) {
    row &= 7;
    return row * 128 + ((u8 ^ row) << 4);
}
__device__ __forceinline__ void hwr16(_Float16* p, int row, int u, _Float16 v) {
    *(_Float16*)((char*)p + ha(row, u >> 3) + (u & 7) * 2) = v;
}
__device__ __forceinline__ f16x8 hrd16(const _Float16* p, int row, int u8) {
    return *(const f16x8*)((const char*)p + ha(row, u8));
}
// 16-row fp16 x plane (pair-step even in rows 0-7, odd in 8-15), XOR on row&7
__device__ __forceinline__ int xaddr(int row, int u8) {
    return row * 128 + ((u8 ^ (row & 7)) << 4);
}
__device__ __forceinline__ void xwr16(_Float16* p, int row, int k, _Float16 v) {
    *(_Float16*)((char*)p + xaddr(row, k >> 3) + (k & 7) * 2) = v;
}
__device__ __forceinline__ f16x8 xrd16(const _Float16* p, int row, int u8) {
    return *(const f16x8*)((const char*)p + xaddr(row, u8));
}

#define MFMA16(A, B, C)  __builtin_amdgcn_mfma_f32_16x16x32_f16((A), (B), (C), 0, 0, 0)

// x-side pass over fp16 plane buffer NB -> DST (2 timesteps; bias folded in)
#define X_PASS(DST, NB) do {                                                  \
    DST[0] = biasr; DST[1] = biasr; DST[2] = biasr; DST[3] = biasr;           \
    {                                                                         \
        const f16x8 ax0 = xrd16(&xp[NB][0], arow, 0 + ksub);                  \
        DST = MFMA16(ax0, WIh0, DST);                                         \
    }                                                                         \
    if (Din > 32) {                                                           \
        const f16x8 ax1 = xrd16(&xp[NB][0], arow, 4 + ksub);                  \
        DST = MFMA16(ax1, WIh1, DST);                                         \
    }                                                                         \
} while (0)

__device__ __forceinline__ f16x8 ldw16(const float* p) {
    const float4 a = *(const float4*)p;
    const float4 b = *(const float4*)(p + 4);
    f16x8 w;
    w[0]=(_Float16)a.x; w[1]=(_Float16)a.y; w[2]=(_Float16)a.z; w[3]=(_Float16)a.w;
    w[4]=(_Float16)b.x; w[5]=(_Float16)b.y; w[6]=(_Float16)b.z; w[7]=(_Float16)b.w;
    return w;
}

__global__ __launch_bounds__(NTHR) void lstm_layer(
    const float* __restrict__ x0,    // layer0 input [B][T][16] fp32, or null
    unsigned*    __restrict__ hseq,  // [T][B][64] packed bf16 hi|lo<<16
    const float* __restrict__ Wih,   // [256][Din]
    const float* __restrict__ Whh,   // [256][64]
    const float* __restrict__ bih,   // [256]
    const float* __restrict__ bhh,   // [256]
    const float* __restrict__ Wout,  // [7][64] (head only)
    const float* __restrict__ bout,  // [7]
    float* __restrict__ out,         // [B][7]
    int Din, int store_h, int do_head)
{
    __shared__ __attribute__((aligned(16))) _Float16 xp[2][16 * 64];
    __shared__ __attribute__((aligned(16))) _Float16 hpf[8 * 64];
    __shared__ __attribute__((aligned(16))) float gts[8 * NG];
    __shared__ __attribute__((aligned(16))) float hf[8 * HID];

    const int tid  = threadIdx.x;
    const int lane = tid & 63;
    const int wid  = tid >> 6;          // 0..15: N-tile index
    const int ncol = wid * 16 + (lane & 15);
    const int ksub = (lane >> 4) & 3;   // k-subgroup of 8
    const int arow = lane & 15;
    const int b0   = blockIdx.x * CB;

    // ---- weight fragments: 1-term fp16, resident for the whole kernel ----
    f16x8 WIh0 = {0,0,0,0,0,0,0,0}, WIh1 = {0,0,0,0,0,0,0,0};
    f16x8 WHh0, WHh1;
    {
        const int k0 = ksub * 8;
        if (k0 < Din) WIh0 = ldw16(Wih + ncol * Din + k0);
        if (Din > 32) WIh1 = ldw16(Wih + ncol * Din + 32 + k0);
        WHh0 = ldw16(Whh + ncol * HID + k0);
        WHh1 = ldw16(Whh + ncol * HID + 32 + k0);
    }
    const float biasr = bih[ncol] + bhh[ncol];

    // ---- zero h plane and both x buffers ----
    hpf[tid & 511] = (_Float16)0.f;
    ((unsigned*)xp)[tid] = 0;     // 1024 u32 = 2048 fp16 = both planes
    __syncthreads();

    // ---- prologue: stage steps 0..3 (pairs {0,1}->buf0, {2,3}->buf1) ----
    if (tid >= 512) {
        const int t2 = tid - 512;
        if (x0) {
            if (t2 < 128) {
                const int b = t2 >> 4, k = t2 & 15;
                #pragma unroll
                for (int s = 0; s < 4; ++s) {
                    const float v = x0[(size_t)(b0 + b) * (T_STEPS * 16) + s * 16 + k];
                    xwr16(&xp[(s >> 1) & 1][0], ((s & 1) << 3) + b, k, (_Float16)v);
                }
            }
        } else {
            const int b = t2 >> 6, u = t2 & 63;
            #pragma unroll
            for (int s = 0; s < 4; ++s) {
                const unsigned p = hseq[(size_t)s * SEQS + (b0 + b) * HID + u];
                const float v = fb(p) + fb(p >> 16);
                xwr16(&xp[(s >> 1) & 1][0], ((s & 1) << 3) + b, u, (_Float16)v);
            }
        }
    }
    __syncthreads();

    // ---- prologue: x contribution (+bias) for pair {0,1} ----
    f32x4 CxCur; X_PASS(CxCur, 0);
    f32x4 CxNext = {0.f, 0.f, 0.f, 0.f};

    float cst = 0.0f;      // c state (threads < 512: one (b,u) cell each)
    unsigned pend = 0;     // deferred hseq store value (h of previous step)

    // running pointers (hoisted addressing) -- identical to R15
    const unsigned* hin = hseq + (size_t)4 * SEQS +
                          (size_t)(b0 + ((tid - 512) >> 6)) * HID + ((tid - 512) & 63);
    const float* xin = x0 ? x0 + (size_t)(b0 + ((tid - 512) >> 4)) * (T_STEPS * 16) +
                             4 * 16 + ((tid - 512) & 15)
                          : nullptr;
    unsigned* hout = hseq + (size_t)(b0 + (tid >> 6)) * HID + (tid & 63);

    for (int t = 0; t < T_STEPS; ++t) {
        // ---- w1: deferred store FIRST (drain hides under MFMA phase) ----
        if (store_h && tid < 512 && t > 0) *(hout - SEQS) = pend;

        // issue x(t+4) prefetch (staging waves)
        float pxn = 0.0f; unsigned phn = 0;
        if (tid >= 512 && t + 4 < T_STEPS) {
            if (x0) {
                if (tid - 512 < 128) pxn = *xin;
            } else {
                phn = *hin;
            }
        }

        // h-side MFMA folded onto Cx
        f32x4 G;
        {
            const f16x8 ah0 = hrd16(hpf, arow, ksub);       // k 0..31
            const f16x8 ah1 = hrd16(hpf, arow, 4 + ksub);   // k 32..63
            G = MFMA16(ah0, WHh0, CxCur);
            G = MFMA16(ah1, WHh1, G);
        }
        // gts writeout: active half-wave by parity, stride-1024B stores
        if ((lane >> 5) == (t & 1)) {
            float* gd = &gts[(((lane >> 4) & 1) * 4) * NG + ncol];
            gd[0]      = G[0];
            gd[NG]     = G[1];
            gd[2 * NG] = G[2];
            gd[3 * NG] = G[3];
        }
        __syncthreads();

        // ---- w2: (even t) x-pass for pair {t+2,t+3} || cell || staging ----
        if ((t & 1) == 0 && t + 2 < T_STEPS) {
            X_PASS(CxNext, ((t >> 1) + 1) & 1);
        }

        if (tid < 512) {
            const int b = tid >> 6, u = tid & 63;
            const float* gsrc = &gts[b * NG + u];
            const float gi = gsrc[0];
            const float gf = gsrc[64];
            const float gg = gsrc[128];
            const float go = gsrc[192];
            cst = sigm(gf) * cst + sigm(gi) * tanh_f(gg);
            const float h = sigm(go) * tanh_f(cst);
            hwr16(hpf, b, u, (_Float16)h);
            if (store_h) {
                const short h_hi = tb(h);
                const short h_lo = tb(h - fb((unsigned)(unsigned short)h_hi));
                pend = (unsigned)(unsigned short)h_hi |
                       ((unsigned)(unsigned short)h_lo << 16);
            }
            if (do_head && t == T_STEPS - 1) hf[b * HID + u] = h;
        } else if (t + 4 < T_STEPS) {
            const int t2 = tid - 512;
            const int wb = (t >> 1) & 1;            // buffer of pair (t+4)>>1
            const int rsh = (t & 1) << 3;           // row half of step t+4
            if (x0) {
                if (t2 < 128) {
                    const int b = t2 >> 4, k = t2 & 15;
                    xwr16(&xp[wb][0], rsh + b, k, (_Float16)pxn);
                }
            } else {
                const int b = t2 >> 6, u = t2 & 63;
                const float v = fb(phn) + fb(phn >> 16);
                xwr16(&xp[wb][0], rsh + b, u, (_Float16)v);
            }
        }
        __syncthreads();

        if (t & 1) CxCur = CxNext;   // pair hand-off (wave-uniform)
        hin += SEQS;
        if (x0) xin += 16;
        hout += SEQS;
    }

    // ---- flush final pending store (slot T-1) ----
    if (store_h && tid < 512) *(hout - SEQS) = pend;

    // ---- head: out = h2[T-1] @ Wout^T + bout ----
    if (do_head && tid < 7 * CB) {
        const int b = tid / 7, o = tid % 7;
        float a = bout[o];
        #pragma unroll
        for (int k = 0; k < HID; ++k)
            a = fmaf(hf[b * HID + k], Wout[o * HID + k], a);
        out[(b0 + b) * 7 + o] = a;
    }
}

extern "C" void kernel_launch(void* const* d_in, const int* in_sizes, int n_in,
                              void* d_out, int out_size, void* d_ws, size_t ws_size,
                              hipStream_t stream) {
    const float* x    = (const float*)d_in[0];
    const float* Wih0 = (const float*)d_in[1];
    const float* Whh0 = (const float*)d_in[2];
    const float* bih0 = (const float*)d_in[3];
    const float* bhh0 = (const float*)d_in[4];
    const float* Wih1 = (const float*)d_in[5];
    const float* Whh1 = (const float*)d_in[6];
    const float* bih1 = (const float*)d_in[7];
    const float* bhh1 = (const float*)d_in[8];
    const float* Wih2 = (const float*)d_in[9];
    const float* Whh2 = (const float*)d_in[10];
    const float* bih2 = (const float*)d_in[11];
    const float* bhh2 = (const float*)d_in[12];
    const float* Wout = (const float*)d_in[13];
    const float* bout = (const float*)d_in[14];
    float* out = (float*)d_out;
    unsigned* hseq = (unsigned*)d_ws;   // needs T*B*64*4 = 268,435,456 B

    const dim3 grid(BATCH / CB), blk(NTHR);
    lstm_layer<<<grid, blk, 0, stream>>>(x, hseq, Wih0, Whh0, bih0, bhh0,
                                         nullptr, nullptr, nullptr, 16, 1, 0);
    lstm_layer<<<grid, blk, 0, stream>>>(nullptr, hseq, Wih1, Whh1, bih1, bhh1,
                                         nullptr, nullptr, nullptr, HID, 1, 0);
    lstm_layer<<<grid, blk, 0, stream>>>(nullptr, hseq, Wih2, Whh2, bih2, bhh2,
                                         Wout, bout, out, HID, 0, 1);
}